// Round 7
// baseline (151.545 us; speedup 1.0000x reference)
//
#include <hip/hip_runtime.h>

// Classwise ECE, probs [N=100000, C=1000] f32, labels [N] i32 -> scalar f32.
// R7: single-pass hist. Correct-events fused into the streaming loop via the
// block-uniform label (s_load): owning thread adds conf_q16 - 65536. LDS slab
// flushed with global atomicAdd into 8 interleaved stage copies (L2-resident,
// exact i32 -> deterministic). 3 dispatches: memset, hist, red2(last-block).

#define NBINS   15
#define THREADS 256
#define TC      512                  // classes per tile (2/thread, float2)
#define TILES   2                    // covers C <= 1024
#define PSTRIDE 31                   // per-thread LDS stride (odd -> all banks)
#define LDSW    (THREADS * PSTRIDE)  // 7936 u32 = 31744 B -> 5 blocks/CU
#define SLOTS   (TC * NBINS)         // 7680 per tile
#define SLAB    (TILES * SLOTS)      // 15360 (class-major linear == slab-linear)
#define NCOPY   8                    // interleaved global stage copies

__global__ __launch_bounds__(THREADS, 5) void ece_hist(
    const float* __restrict__ probs, const int* __restrict__ labels,
    int N, int C, int R,
    int* __restrict__ stage)                  // [NCOPY][SLAB] q16 sums
{
    __shared__ unsigned sA[LDSW];
    const int t = threadIdx.x;
    #pragma unroll
    for (int i = t; i < LDSW; i += THREADS) sA[i] = 0u;
    __syncthreads();

    const int chunk = blockIdx.x;
    const int tile  = blockIdx.y;
    const int cls0  = tile * TC + 2 * t;
    const int col   = (cls0 <= C - 2) ? cls0 : (C - 2);  // dead cols unread later

    const int r0 = chunk * R;
    int rend = N - r0; if (rend > R) rend = R; if (rend < 0) rend = 0;

    const float2* p = (const float2*)(probs + (size_t)r0 * C + col);
    const size_t rowstep = (size_t)(C >> 1);
    unsigned* s0 = sA + t * PSTRIDE;          // class0 bins [0,15), class1 [15,30)

    #pragma unroll 8
    for (int r = 0; r < rend; ++r) {
        float2 v = p[(size_t)r * rowstep];
        int lab = labels[r0 + r];             // block-uniform -> scalar load

        int b0 = (int)(v.x * 15.0f);          // trunc==floor (v>=0) == ref ceil-1
        b0 = b0 < NBINS - 1 ? b0 : NBINS - 1;
        unsigned c0 = (unsigned)fmaf(v.x, 65536.0f, 0.5f);
        c0 += (lab == cls0) ? (unsigned)(-65536) : 0u;   // fused correct-event
        atomicAdd(&s0[b0], (v.x > 0.0f) ? c0 : 0u);      // ds_add, private slot

        int b1 = (int)(v.y * 15.0f);
        b1 = b1 < NBINS - 1 ? b1 : NBINS - 1;
        unsigned c1 = (unsigned)fmaf(v.y, 65536.0f, 0.5f);
        c1 += (lab == cls0 + 1) ? (unsigned)(-65536) : 0u;
        atomicAdd(&s0[NBINS + b1], (v.y > 0.0f) ? c1 : 0u);
    }
    __syncthreads();

    // Flush: class-major linear slab == padded-LDS unpack; lane-consecutive
    // global atomics into stage copy (chunk & 7). Exact i32 -> deterministic.
    int* dst = stage + (size_t)(chunk & (NCOPY - 1)) * SLAB + (size_t)tile * SLOTS;
    #pragma unroll
    for (int i = t; i < SLOTS; i += THREADS) {
        int owner = i / (2 * NBINS), j = i - owner * (2 * NBINS);
        int val = (int)sA[owner * PSTRIDE + j];
        if (val) atomicAdd(&dst[i], val);
    }
}

// contrib = |sum_q16| / 65536 / N ; last finishing block reduces blockSums.
__global__ __launch_bounds__(256) void ece_red2(
    const int* __restrict__ stage, int C, int N, int nb,
    float* __restrict__ blockSums, unsigned* __restrict__ counter,
    float* __restrict__ out)
{
    int i = blockIdx.x * 256 + threadIdx.x;
    float contrib = 0.0f;
    if (i < C * NBINS) {
        long long s = 0;
        #pragma unroll
        for (int g = 0; g < NCOPY; ++g)
            s += (long long)stage[(size_t)g * SLAB + i];
        contrib = fabsf((float)s * (1.0f / 65536.0f)) * (1.0f / (float)N);
    }
    for (int o = 32; o; o >>= 1) contrib += __shfl_down(contrib, o);
    __shared__ float ws4[4];
    const int wid = threadIdx.x >> 6, lane = threadIdx.x & 63;
    if (lane == 0) ws4[wid] = contrib;
    __syncthreads();
    if (threadIdx.x == 0) {
        blockSums[blockIdx.x] = ws4[0] + ws4[1] + ws4[2] + ws4[3];
        __threadfence();
        unsigned old = atomicAdd(counter, 1u);
        if (old == (unsigned)(nb - 1)) {
            __threadfence();
            double s = 0.0;
            for (int b = 0; b < nb; ++b) s += (double)blockSums[b];
            out[0] = (float)(s / (double)C);
        }
    }
}

extern "C" void kernel_launch(void* const* d_in, const int* in_sizes, int n_in,
                              void* d_out, int out_size, void* d_ws, size_t ws_size,
                              hipStream_t stream) {
    const float* probs  = (const float*)d_in[0];
    const int*   labels = (const int*)d_in[1];
    const int N = in_sizes[1];               // 100000
    const int C = in_sizes[0] / N;           // 1000

    // ws: [counter u32 @0][blockSums f32[128] @512] pad 4096 | stage i32[8][SLAB]
    const size_t headBytes  = 4096;
    const size_t stageBytes = (size_t)NCOPY * SLAB * 4;     // 491520

    unsigned* counter   = (unsigned*)d_ws;
    float*    blockSums = (float*)((char*)d_ws + 512);
    int*      stage     = (int*)((char*)d_ws + headBytes);

    int chunks = 500;                        // 500x2 = 1000 blocks ~ 4/CU
    const int R   = (N + chunks - 1) / chunks;   // 200 (q16 sums fit i32)
    const int nb2 = (C * NBINS + 255) / 256;     // 59 (<=128 blockSums slots)

    hipMemsetAsync(d_ws, 0, headBytes + stageBytes, stream);
    dim3 hgrid(chunks, TILES);
    ece_hist<<<hgrid, THREADS, 0, stream>>>(probs, labels, N, C, R, stage);
    ece_red2<<<nb2, 256, 0, stream>>>(stage, C, N, nb2, blockSums, counter,
                                      (float*)d_out);
}

// Round 8
// 99.461 us; speedup vs baseline: 1.5237x; 1.5237x over previous
//
#include <hip/hip_runtime.h>

// Classwise ECE, probs [N=100000, C=1000] f32, labels [N] i32 -> scalar f32.
// R8: fully-contiguous block streaming. 512 thr/block; threads 0..499 load
// float2 (cols 2t,2t+1) -> each block reads a contiguous R*4000-B region.
// Correct-events fused via block-uniform label. Stride-31 LDS (conflict-free),
// 2 blocks/CU = 16 waves. Store-flush + red1 + red2(last-block). 3 dispatches,
// integer accumulation throughout (bit-deterministic).

#define NBINS   15
#define THREADS 512
#define CPT     2                    // classes per thread (float2)
#define TC      (THREADS * CPT)      // 1024 >= C, one block covers all classes
#define PSTRIDE 31                   // 30 slots + 1 pad (odd -> all 32 banks)
#define LDSW    (THREADS * PSTRIDE)  // 15872 u32 = 63488 B -> 2 blocks/CU
#define SLAB    (TC * NBINS)         // 15360 i32 per chunk
#define NGROUP  16

__global__ __launch_bounds__(THREADS, 4) void ece_hist(
    const float* __restrict__ probs, const int* __restrict__ labels,
    int N, int C, int R,
    int* __restrict__ partial)                // [chunks][SLAB] signed q16 sums
{
    __shared__ unsigned sA[LDSW];
    const int t = threadIdx.x;
    #pragma unroll
    for (int i = t; i < LDSW; i += THREADS) sA[i] = 0u;
    __syncthreads();

    const int cls0 = 2 * t;
    const bool live = (cls0 + 1 < C);         // threads 500..511 idle on loads
    const int col  = live ? cls0 : 0;

    const int r0 = blockIdx.x * R;
    int rend = N - r0; if (rend > R) rend = R; if (rend < 0) rend = 0;

    const float2* p = (const float2*)(probs + (size_t)r0 * C + col);
    const size_t rowstep = (size_t)(C >> 1);
    unsigned* s0 = sA + t * PSTRIDE;

    float2 buf[8];
    int r = 0;
    for (; r + 8 <= rend; r += 8) {
        #pragma unroll
        for (int k = 0; k < 8; ++k)
            buf[k] = live ? p[(size_t)(r + k) * rowstep] : make_float2(0.f, 0.f);
        #pragma unroll
        for (int k = 0; k < 8; ++k) {
            float2 v = buf[k];
            int lab = labels[r0 + r + k];     // block-uniform -> s_load

            int b0 = (int)(v.x * 15.0f);      // trunc==floor (v>=0) == ref ceil-1
            b0 = b0 < NBINS - 1 ? b0 : NBINS - 1;
            unsigned c0 = (unsigned)fmaf(v.x, 65536.0f, 0.5f);
            c0 += (lab == cls0) ? (unsigned)(-65536) : 0u;   // fused correct
            atomicAdd(&s0[b0], (v.x > 0.0f) ? c0 : 0u);      // ds_add, private

            int b1 = (int)(v.y * 15.0f);
            b1 = b1 < NBINS - 1 ? b1 : NBINS - 1;
            unsigned c1 = (unsigned)fmaf(v.y, 65536.0f, 0.5f);
            c1 += (lab == cls0 + 1) ? (unsigned)(-65536) : 0u;
            atomicAdd(&s0[NBINS + b1], (v.y > 0.0f) ? c1 : 0u);
        }
    }
    for (; r < rend; ++r) {                   // tail (only if R % 8 != 0)
        float2 v = live ? p[(size_t)r * rowstep] : make_float2(0.f, 0.f);
        int lab = labels[r0 + r];
        int b0 = (int)(v.x * 15.0f);
        b0 = b0 < NBINS - 1 ? b0 : NBINS - 1;
        unsigned c0 = (unsigned)fmaf(v.x, 65536.0f, 0.5f);
        c0 += (lab == cls0) ? (unsigned)(-65536) : 0u;
        atomicAdd(&s0[b0], (v.x > 0.0f) ? c0 : 0u);
        int b1 = (int)(v.y * 15.0f);
        b1 = b1 < NBINS - 1 ? b1 : NBINS - 1;
        unsigned c1 = (unsigned)fmaf(v.y, 65536.0f, 0.5f);
        c1 += (lab == cls0 + 1) ? (unsigned)(-65536) : 0u;
        atomicAdd(&s0[NBINS + b1], (v.y > 0.0f) ? c1 : 0u);
    }
    __syncthreads();

    // Flush padded LDS -> linear class-major (coalesced stores).
    int* dst = partial + (size_t)blockIdx.x * SLAB;
    #pragma unroll
    for (int i = t; i < SLAB; i += THREADS) {
        int owner = i / (2 * NBINS), j = i - owner * (2 * NBINS);
        dst[i] = (int)sA[owner * PSTRIDE + j];
    }
}

// Stage 1: per chunk-group signed partial sums (i32, exact); zeroes counter.
__global__ __launch_bounds__(256) void ece_red1(
    const int* __restrict__ partial, int chunks, int gsz,
    int* __restrict__ stage1, unsigned* __restrict__ counter)
{
    if (blockIdx.x == 0 && blockIdx.y == 0 && threadIdx.x == 0) *counter = 0u;
    int i = blockIdx.x * 256 + threadIdx.x;   // grid.x*256 == SLAB exactly
    int g = blockIdx.y;
    int k0 = g * gsz;
    int k1 = k0 + gsz; if (k1 > chunks) k1 = chunks;
    int s = 0;
    #pragma unroll 8
    for (int k = k0; k < k1; ++k)
        s += partial[(size_t)k * SLAB + i];
    stage1[(size_t)g * SLAB + i] = s;
}

// Stage 2: contrib = |sum_q16| / 65536 / N ; last finishing block reduces.
__global__ __launch_bounds__(256) void ece_red2(
    const int* __restrict__ stage1, int C, int N, int nb,
    float* __restrict__ blockSums, unsigned* __restrict__ counter,
    float* __restrict__ out)
{
    int i = blockIdx.x * 256 + threadIdx.x;
    float contrib = 0.0f;
    if (i < C * NBINS) {
        long long s = 0;
        #pragma unroll
        for (int g = 0; g < NGROUP; ++g)
            s += (long long)stage1[(size_t)g * SLAB + i];
        contrib = fabsf((float)s * (1.0f / 65536.0f)) * (1.0f / (float)N);
    }
    for (int o = 32; o; o >>= 1) contrib += __shfl_down(contrib, o);
    __shared__ float ws4[4];
    const int wid = threadIdx.x >> 6, lane = threadIdx.x & 63;
    if (lane == 0) ws4[wid] = contrib;
    __syncthreads();
    if (threadIdx.x == 0) {
        blockSums[blockIdx.x] = ws4[0] + ws4[1] + ws4[2] + ws4[3];
        __threadfence();
        unsigned old = atomicAdd(counter, 1u);
        if (old == (unsigned)(nb - 1)) {
            __threadfence();
            double s = 0.0;
            for (int b = 0; b < nb; ++b) s += (double)blockSums[b];
            out[0] = (float)(s / (double)C);
        }
    }
}

extern "C" void kernel_launch(void* const* d_in, const int* in_sizes, int n_in,
                              void* d_out, int out_size, void* d_ws, size_t ws_size,
                              hipStream_t stream) {
    const float* probs  = (const float*)d_in[0];
    const int*   labels = (const int*)d_in[1];
    const int N = in_sizes[1];               // 100000
    const int C = in_sizes[0] / N;           // 1000

    // ws: [counter u32 @0][blockSums f32[128] @512] pad 4096
    //     | stage1 i32[16][SLAB] | partial i32[chunks][SLAB]
    const size_t headBytes   = 4096;
    const size_t stage1Bytes = (size_t)NGROUP * SLAB * 4;   // 983 KB
    const size_t off_partial = headBytes + stage1Bytes;
    const size_t slabBytes   = (size_t)SLAB * 4;            // 61440

    unsigned* counter   = (unsigned*)d_ws;
    float*    blockSums = (float*)((char*)d_ws + 512);
    int*      stage1    = (int*)((char*)d_ws + headBytes);
    int*      partial   = (int*)((char*)d_ws + off_partial);

    long long avail = (long long)ws_size - (long long)off_partial;
    int chunks = (int)(avail / (long long)slabBytes);
    if (chunks > 500) chunks = 500;          // 500 blocks = 2/CU, R = 200
    if (chunks < 4) chunks = 4;              // R <= 25000 keeps q16 sums in i32
    const int R   = (N + chunks - 1) / chunks;
    const int gsz = (chunks + NGROUP - 1) / NGROUP;
    const int nb2 = (C * NBINS + 255) / 256; // 59 (<=128 blockSums slots)

    ece_hist<<<chunks, THREADS, 0, stream>>>(probs, labels, N, C, R, partial);
    dim3 r1grid(SLAB / 256, NGROUP);         // 60 x 16
    ece_red1<<<r1grid, 256, 0, stream>>>(partial, chunks, gsz, stage1, counter);
    ece_red2<<<nb2, 256, 0, stream>>>(stage1, C, N, nb2, blockSums, counter,
                                      (float*)d_out);
}

// Round 9
// 95.461 us; speedup vs baseline: 1.5875x; 1.0419x over previous
//
#include <hip/hip_runtime.h>

// Classwise ECE, probs [N=100000, C=1000] f32, labels [N] i32 -> scalar f32.
// R9: 2 dispatches. hist: contiguous 784KB/block streaming (512 thr, float2,
// stride-31 LDS, fused correct-events via block-uniform label), chunks=512 =
// exactly 2 blocks/CU. red: single fused kernel, 60 blocks x 1024 thr; each
// block owns 256 slots, 4 chunk-quarters summed i32 -> LDS -> i64 -> contrib
// -> exact u64 q40 atomicAdd -> last block writes out. Bit-deterministic.

#define NBINS   15
#define THREADS 512
#define TC      1024                 // classes covered per block (2/thread)
#define PSTRIDE 31                   // 30 slots + 1 pad (odd -> all 32 banks)
#define LDSW    (THREADS * PSTRIDE)  // 15872 u32 = 63488 B -> 2 blocks/CU
#define SLAB    (TC * NBINS)         // 15360 i32 per chunk
#define SEGS    (SLAB / 256)         // 60 red blocks
#define Q40     1099511627776.0f     // 2^40

__global__ __launch_bounds__(THREADS, 4) void ece_hist(
    const float* __restrict__ probs, const int* __restrict__ labels,
    int N, int C, int R,
    int* __restrict__ partial,               // [chunks][SLAB] signed q16 sums
    unsigned long long* __restrict__ accum,  // zeroed here (graph-replay safe)
    unsigned* __restrict__ doneCnt)
{
    __shared__ unsigned sA[LDSW];
    const int t = threadIdx.x;
    if (blockIdx.x == 0 && t == 0) { *accum = 0ull; *doneCnt = 0u; }
    #pragma unroll
    for (int i = t; i < LDSW; i += THREADS) sA[i] = 0u;
    __syncthreads();

    const int cls0 = 2 * t;
    const bool live = (cls0 + 1 < C);        // threads past C idle on loads
    const int col  = live ? cls0 : 0;

    const int r0 = blockIdx.x * R;
    int rend = N - r0; if (rend > R) rend = R; if (rend < 0) rend = 0;

    const float2* p = (const float2*)(probs + (size_t)r0 * C + col);
    const size_t rowstep = (size_t)(C >> 1);
    unsigned* s0 = sA + t * PSTRIDE;

    float2 buf[8];
    int r = 0;
    for (; r + 8 <= rend; r += 8) {
        #pragma unroll
        for (int k = 0; k < 8; ++k)
            buf[k] = live ? p[(size_t)(r + k) * rowstep] : make_float2(0.f, 0.f);
        #pragma unroll
        for (int k = 0; k < 8; ++k) {
            float2 v = buf[k];
            int lab = labels[r0 + r + k];    // block-uniform -> s_load

            int b0 = (int)(v.x * 15.0f);     // trunc==floor (v>=0) == ref ceil-1
            b0 = b0 < NBINS - 1 ? b0 : NBINS - 1;
            unsigned c0 = (unsigned)fmaf(v.x, 65536.0f, 0.5f);
            c0 += (lab == cls0) ? (unsigned)(-65536) : 0u;   // fused correct
            atomicAdd(&s0[b0], (v.x > 0.0f) ? c0 : 0u);      // ds_add, private

            int b1 = (int)(v.y * 15.0f);
            b1 = b1 < NBINS - 1 ? b1 : NBINS - 1;
            unsigned c1 = (unsigned)fmaf(v.y, 65536.0f, 0.5f);
            c1 += (lab == cls0 + 1) ? (unsigned)(-65536) : 0u;
            atomicAdd(&s0[NBINS + b1], (v.y > 0.0f) ? c1 : 0u);
        }
    }
    for (; r < rend; ++r) {                  // tail
        float2 v = live ? p[(size_t)r * rowstep] : make_float2(0.f, 0.f);
        int lab = labels[r0 + r];
        int b0 = (int)(v.x * 15.0f);
        b0 = b0 < NBINS - 1 ? b0 : NBINS - 1;
        unsigned c0 = (unsigned)fmaf(v.x, 65536.0f, 0.5f);
        c0 += (lab == cls0) ? (unsigned)(-65536) : 0u;
        atomicAdd(&s0[b0], (v.x > 0.0f) ? c0 : 0u);
        int b1 = (int)(v.y * 15.0f);
        b1 = b1 < NBINS - 1 ? b1 : NBINS - 1;
        unsigned c1 = (unsigned)fmaf(v.y, 65536.0f, 0.5f);
        c1 += (lab == cls0 + 1) ? (unsigned)(-65536) : 0u;
        atomicAdd(&s0[NBINS + b1], (v.y > 0.0f) ? c1 : 0u);
    }
    __syncthreads();

    // Flush padded LDS -> linear class-major (coalesced stores).
    int* dst = partial + (size_t)blockIdx.x * SLAB;
    #pragma unroll
    for (int i = t; i < SLAB; i += THREADS) {
        int owner = i / (2 * NBINS), j = i - owner * (2 * NBINS);
        dst[i] = (int)sA[owner * PSTRIDE + j];
    }
}

// Fused reduce: 60 blocks x 1024 thr. Block owns slots [seg*256, seg*256+256);
// thread (q = t>>8, j = t&255) sums chunk-quarter q for slot j (i32, exact),
// LDS exchange, i64 combine, contrib = |sum|/65536/N, block-reduce, one q40
// u64 atomicAdd per block; last finishing block writes the scalar.
__global__ __launch_bounds__(1024, 1) void ece_red(
    const int* __restrict__ partial, int chunks, int C, int N,
    unsigned long long* __restrict__ accum, unsigned* __restrict__ doneCnt,
    float* __restrict__ out)
{
    __shared__ int sq[4][256];
    __shared__ float ws4[4];
    const int t = threadIdx.x;
    const int q = t >> 8, j = t & 255;
    const int slot = blockIdx.x * 256 + j;

    const int gsz = (chunks + 3) >> 2;
    int k0 = q * gsz;
    int k1 = k0 + gsz; if (k1 > chunks) k1 = chunks;
    int s = 0;
    #pragma unroll 8
    for (int k = k0; k < k1; ++k)
        s += partial[(size_t)k * SLAB + slot];
    sq[q][j] = s;
    __syncthreads();

    float contrib = 0.0f;
    if (t < 256) {
        long long tot = (long long)sq[0][t] + sq[1][t] + sq[2][t] + sq[3][t];
        if (slot - j + t < C * NBINS)        // slot index for thread t
            contrib = fabsf((float)tot * (1.0f / 65536.0f)) * (1.0f / (float)N);
        for (int o = 32; o; o >>= 1) contrib += __shfl_down(contrib, o);
        if ((t & 63) == 0) ws4[t >> 6] = contrib;
    }
    __syncthreads();
    if (t == 0) {
        float bs = ws4[0] + ws4[1] + ws4[2] + ws4[3];
        atomicAdd(accum, (unsigned long long)(bs * Q40));  // exact int add
        __threadfence();
        if (atomicAdd(doneCnt, 1u) == (unsigned)(SEGS - 1)) {
            __threadfence();
            unsigned long long a = atomicAdd(accum, 0ull); // atomic read
            out[0] = (float)((double)a * (1.0 / (double)Q40) / (double)C);
        }
    }
}

extern "C" void kernel_launch(void* const* d_in, const int* in_sizes, int n_in,
                              void* d_out, int out_size, void* d_ws, size_t ws_size,
                              hipStream_t stream) {
    const float* probs  = (const float*)d_in[0];
    const int*   labels = (const int*)d_in[1];
    const int N = in_sizes[1];               // 100000
    const int C = in_sizes[0] / N;           // 1000

    // ws: [accum u64 @0][doneCnt u32 @8] pad 4096 | partial i32[chunks][SLAB]
    const size_t headBytes = 4096;
    const size_t slabBytes = (size_t)SLAB * 4;              // 61440

    unsigned long long* accum   = (unsigned long long*)d_ws;
    unsigned*           doneCnt = (unsigned*)((char*)d_ws + 8);
    int*                partial = (int*)((char*)d_ws + headBytes);

    long long avail = (long long)ws_size - (long long)headBytes;
    int chunks = (int)(avail / (long long)slabBytes);
    if (chunks > 512) chunks = 512;          // 512 blocks = exactly 2/CU
    if (chunks < 4) chunks = 4;              // quarter-sums stay in i32
    const int R = (N + chunks - 1) / chunks; // 196 at chunks=512

    ece_hist<<<chunks, THREADS, 0, stream>>>(probs, labels, N, C, R,
                                             partial, accum, doneCnt);
    ece_red<<<SEGS, 1024, 0, stream>>>(partial, chunks, C, N,
                                       accum, doneCnt, (float*)d_out);
}

// Round 11
// 89.136 us; speedup vs baseline: 1.7001x; 1.0709x over previous
//
#include <hip/hip_runtime.h>

// Classwise ECE, probs [N=100000, C=1000] f32, labels [N] i32 -> scalar f32.
// R11 (= R10 design, macro bug fixed): 2 dispatches. hist: two-phase
// software-pipelined contiguous streaming (512 thr, float2, 8 loads in
// flight), q7 conf sums in stride-31 LDS, correct-events fused via
// block-uniform label, flush packs i16 PAIRS into u32 (15.7 MB slab).
// red: 120 blocks x 1024 thr, integer folds, q40 u64 atomic, last-block
// writes scalar. Bit-deterministic.

#define NBINS   15
#define THREADS 512
#define PSTRIDE 31                   // 30 slots + 1 pad (odd -> all 32 banks)
#define LDSW    (THREADS * PSTRIDE)  // 15872 u32 = 63488 B -> 2 blocks/CU
#define SLAB    (1024 * NBINS)       // 15360 logical slots per chunk
#define SLABH   (SLAB / 2)           // 7680 packed u32 per chunk
#define RBLK    120                  // red blocks: 120 * 64 pairs = SLABH
#define Q40     1099511627776.0f     // 2^40

__global__ __launch_bounds__(THREADS, 4) void ece_hist(
    const float* __restrict__ probs, const int* __restrict__ labels,
    int N, int C, int R,
    unsigned* __restrict__ partial,          // [chunks][SLABH] i16-pair packs
    unsigned long long* __restrict__ accum,
    unsigned* __restrict__ doneCnt)
{
    __shared__ unsigned sA[LDSW];
    const int t = threadIdx.x;
    if (blockIdx.x == 0 && t == 0) { *accum = 0ull; *doneCnt = 0u; }
    #pragma unroll
    for (int i = t; i < LDSW; i += THREADS) sA[i] = 0u;
    __syncthreads();

    const int cls0 = 2 * t;
    const bool live = (cls0 + 1 < C);        // threads past C idle on loads
    const int col  = live ? cls0 : 0;

    const int r0 = blockIdx.x * R;
    int rend = N - r0; if (rend > R) rend = R; if (rend < 0) rend = 0;

    const float2* p = (const float2*)(probs + (size_t)r0 * C + col);
    const size_t rowstep = (size_t)(C >> 1);
    unsigned* s0 = sA + t * PSTRIDE;

    float2 bufA[8], bufB[8];
    int    labA[8], labB[8];

    // All loops below are fully unrolled -> constant indices -> registers.
    #define LOADG(buf, lab, base)                                          \
        _Pragma("unroll")                                                  \
        for (int k = 0; k < 8; ++k) {                                      \
            int ri = (base) + k;                                           \
            ri = ri < rend ? ri : rend - 1;                                \
            buf[k] = live ? p[(size_t)ri * rowstep] : make_float2(0.f,0.f);\
            lab[k] = labels[r0 + ri];                                      \
        }

    #define PROC1(v, lb)                                                   \
        {                                                                  \
            int b0 = (int)(v.x * 15.0f);  /* trunc==floor == ref ceil-1 */ \
            b0 = b0 < NBINS - 1 ? b0 : NBINS - 1;                          \
            unsigned c0 = (unsigned)fmaf(v.x, 128.0f, 0.5f);               \
            c0 += ((lb) == cls0) ? (unsigned)(-128) : 0u;                  \
            atomicAdd(&s0[b0], (v.x > 0.0f) ? c0 : 0u);                    \
            int b1 = (int)(v.y * 15.0f);                                   \
            b1 = b1 < NBINS - 1 ? b1 : NBINS - 1;                          \
            unsigned c1 = (unsigned)fmaf(v.y, 128.0f, 0.5f);               \
            c1 += ((lb) == cls0 + 1) ? (unsigned)(-128) : 0u;              \
            atomicAdd(&s0[NBINS + b1], (v.y > 0.0f) ? c1 : 0u);            \
        }

    #define PROCG(buf, lab)                                                \
        _Pragma("unroll")                                                  \
        for (int k = 0; k < 8; ++k) PROC1(buf[k], lab[k])

    int r = 0;
    if (rend >= 16) {
        LOADG(bufA, labA, 0);
        for (; r + 16 <= rend; r += 16) {
            LOADG(bufB, labB, r + 8);        // B loads in flight over PROC(A)
            PROCG(bufA, labA);
            LOADG(bufA, labA, r + 16);       // clamped; consumed next iter
            PROCG(bufB, labB);
        }
    }
    for (; r < rend; ++r) {                  // scalar tail (<16 rows)
        float2 v = live ? p[(size_t)r * rowstep] : make_float2(0.f, 0.f);
        int lb = labels[r0 + r];
        PROC1(v, lb);
    }
    __syncthreads();

    // Flush: pack slot pairs (2j, 2j+1) as two i16 in one u32, class-major.
    unsigned* dst = partial + (size_t)blockIdx.x * SLABH;
    #pragma unroll
    for (int i = t; i < SLABH; i += THREADS) {
        int owner = i / 15, j = 2 * (i - owner * 15);
        unsigned v0 = sA[owner * PSTRIDE + j];
        unsigned v1 = sA[owner * PSTRIDE + j + 1];
        dst[i] = (v0 & 0xFFFFu) | (v1 << 16);
    }
}

// red: 120 blocks x 1024 thr; block owns 64 packed pairs. Thread (g=t>>6,
// pj=t&63) sums chunk-group g (i32 exact), LDS exchange, 64 threads combine,
// contrib = (|s0|+|s1|)/128/N, wave-reduce, q40 u64 atomic; last block out.
__global__ __launch_bounds__(1024, 1) void ece_red(
    const unsigned* __restrict__ partial, int chunks, int C, int N,
    unsigned long long* __restrict__ accum, unsigned* __restrict__ doneCnt,
    float* __restrict__ out)
{
    __shared__ int sq0[16][64];
    __shared__ int sq1[16][64];
    const int t = threadIdx.x;
    const int g = t >> 6, pj = t & 63;
    const int pair = blockIdx.x * 64 + pj;

    const int gsz = (chunks + 15) >> 4;
    int k0 = g * gsz;
    int k1 = k0 + gsz; if (k1 > chunks) k1 = chunks;
    int a0 = 0, a1 = 0;
    #pragma unroll 8
    for (int k = k0; k < k1; ++k) {
        unsigned w = partial[(size_t)k * SLABH + pair];
        a0 += (int)(short)(w & 0xFFFFu);
        a1 += (int)(short)(w >> 16);
    }
    sq0[g][pj] = a0;
    sq1[g][pj] = a1;
    __syncthreads();

    if (t < 64) {
        int t0 = 0, t1 = 0;
        #pragma unroll
        for (int gg = 0; gg < 16; ++gg) { t0 += sq0[gg][t]; t1 += sq1[gg][t]; }
        int slot0 = (blockIdx.x * 64 + t) * 2;
        float contrib = 0.0f;
        if (slot0     < C * NBINS) contrib += fabsf((float)t0);
        if (slot0 + 1 < C * NBINS) contrib += fabsf((float)t1);
        contrib *= (1.0f / 128.0f) * (1.0f / (float)N);
        for (int o = 32; o; o >>= 1) contrib += __shfl_down(contrib, o);
        if (t == 0) {
            atomicAdd(accum, (unsigned long long)(contrib * Q40)); // exact
            __threadfence();
            if (atomicAdd(doneCnt, 1u) == (unsigned)(RBLK - 1)) {
                __threadfence();
                unsigned long long a = atomicAdd(accum, 0ull);     // atomic read
                out[0] = (float)((double)a * (1.0 / (double)Q40) / (double)C);
            }
        }
    }
}

extern "C" void kernel_launch(void* const* d_in, const int* in_sizes, int n_in,
                              void* d_out, int out_size, void* d_ws, size_t ws_size,
                              hipStream_t stream) {
    const float* probs  = (const float*)d_in[0];
    const int*   labels = (const int*)d_in[1];
    const int N = in_sizes[1];               // 100000
    const int C = in_sizes[0] / N;           // 1000

    // ws: [accum u64 @0][doneCnt u32 @8] pad 4096 | partial u32[chunks][SLABH]
    const size_t headBytes = 4096;
    const size_t slabBytes = (size_t)SLABH * 4;             // 30720

    unsigned long long* accum   = (unsigned long long*)d_ws;
    unsigned*           doneCnt = (unsigned*)((char*)d_ws + 8);
    unsigned*           partial = (unsigned*)((char*)d_ws + headBytes);

    long long avail = (long long)ws_size - (long long)headBytes;
    int chunks = (int)(avail / (long long)slabBytes);
    if (chunks > 512) chunks = 512;          // 512 blocks = exactly 2/CU
    if (chunks < 393) chunks = 393;          // R <= 255 keeps q7 sums in i16
    const int R = (N + chunks - 1) / chunks; // 196 at chunks=512

    ece_hist<<<chunks, THREADS, 0, stream>>>(probs, labels, N, C, R,
                                             partial, accum, doneCnt);
    ece_red<<<RBLK, 1024, 0, stream>>>(partial, chunks, C, N,
                                       accum, doneCnt, (float*)d_out);
}